// Round 10
// baseline (141.947 us; speedup 1.0000x reference)
//
#include <hip/hip_runtime.h>
#include <hip/hip_bf16.h>
#include <stdint.h>

#define HIDDEN 1024
#define NHEADS 16
#define DHEAD  64
#define BATCH  2
#define SEQ    2048
#define MROWS  (BATCH*SEQ)   // 4096
#define QKVC   (3*HIDDEN)    // 3072

typedef unsigned short u16;
typedef unsigned int   u32;
typedef __bf16 bf16x8 __attribute__((ext_vector_type(8)));
typedef __bf16 bf16x2 __attribute__((ext_vector_type(2)));
typedef float  f32x4  __attribute__((ext_vector_type(4)));
typedef float  f32x16 __attribute__((ext_vector_type(16)));
typedef short  s16x4  __attribute__((ext_vector_type(4)));
typedef u16    u16x8  __attribute__((ext_vector_type(8)));
typedef u32    u32x2  __attribute__((ext_vector_type(2)));

typedef const __attribute__((address_space(1))) void gvoid_t;
typedef       __attribute__((address_space(3))) void lvoid_t;

__device__ __forceinline__ gvoid_t* to_glob(const void* p){
  return (gvoid_t*)(uintptr_t)p;
}
__device__ __forceinline__ lvoid_t* to_lds(void* p){
  return (lvoid_t*)(uintptr_t)p;
}
__device__ __forceinline__ u32 lds_off(const void* p){
  return (u32)(uintptr_t)p;
}

// native f32->bf16 (hardware RNE cvt on gfx950)
__device__ __forceinline__ u16 f2bf(float x){
  __bf16 h = (__bf16)x;
  return __builtin_bit_cast(u16, h);
}
// packed f32x2 -> bf16x2 word (compiler emits v_cvt_pk_bf16_f32)
__device__ __forceinline__ u32 pk2(float a, float b){
  bf16x2 t = { (__bf16)a, (__bf16)b };
  return __builtin_bit_cast(u32, t);
}

#define MFMA32(a, b, c) __builtin_amdgcn_mfma_f32_32x32x16_bf16(a, b, c, 0, 0, 0)

// ---------------- fp32 -> bf16 conversion, all 3 inputs in one launch ----------------
#define CVT_N0 1048576   // enc      (4M f32 / 4)
#define CVT_N1  786432   // attn_w   (3M f32 / 4)
#define CVT_N2  262144   // out_w    (1M f32 / 4)
__global__ __launch_bounds__(256) void k_cvt3(const float* __restrict__ e,
                                              const float* __restrict__ wa,
                                              const float* __restrict__ wo,
                                              u16* __restrict__ eb,
                                              u16* __restrict__ wab,
                                              u16* __restrict__ wob){
  int i = blockIdx.x * 256 + threadIdx.x;
  const float* src; u16* dst;
  if (i < CVT_N0){ src = e; dst = eb; }
  else if (i < CVT_N0 + CVT_N1){ i -= CVT_N0; src = wa; dst = wab; }
  else if (i < CVT_N0 + CVT_N1 + CVT_N2){ i -= CVT_N0 + CVT_N1; src = wo; dst = wob; }
  else return;
  const float4 v = reinterpret_cast<const float4*>(src)[i];
  ushort4 o;
  o.x = f2bf(v.x); o.y = f2bf(v.y); o.z = f2bf(v.z); o.w = f2bf(v.w);
  reinterpret_cast<ushort4*>(dst)[i] = o;
}

// ---------------- bf16 GEMM, C = A * B^T + bias (unchanged from R6) ----------------
template<int NC, bool BF16OUT>
__global__ __launch_bounds__(256) void k_gemm(const u16* __restrict__ A,
                                              const u16* __restrict__ B,
                                              const float* __restrict__ bias,
                                              void* __restrict__ C){
  constexpr int K = HIDDEN;
  __shared__ u16 As[2][128*32];
  __shared__ u16 Bs[2][128*32];
  const int m0 = blockIdx.x * 128;
  const int n0 = blockIdx.y * 128;
  const int tid = threadIdx.x;
  const int w = tid >> 6, l = tid & 63;
  const int wr = w >> 1, wc = w & 1;

  const f32x4 fz = {0.f, 0.f, 0.f, 0.f};
  f32x4 acc[4][4];
  #pragma unroll
  for (int i = 0; i < 4; ++i)
    #pragma unroll
    for (int j = 0; j < 4; ++j) acc[i][j] = fz;

  const u16* ap = A + (size_t)(m0 + (tid >> 2)) * K + (tid & 3) * 8;
  const u16* bp = B + (size_t)(n0 + (tid >> 2)) * K + (tid & 3) * 8;

  auto stage = [&](int k0, int buf){
    __builtin_amdgcn_global_load_lds(to_glob(ap + k0),        to_lds(&As[buf][w*512]),        16, 0, 0);
    __builtin_amdgcn_global_load_lds(to_glob(ap + 64*K + k0), to_lds(&As[buf][2048 + w*512]), 16, 0, 0);
    __builtin_amdgcn_global_load_lds(to_glob(bp + k0),        to_lds(&Bs[buf][w*512]),        16, 0, 0);
    __builtin_amdgcn_global_load_lds(to_glob(bp + 64*K + k0), to_lds(&Bs[buf][2048 + w*512]), 16, 0, 0);
  };

  stage(0, 0);
  __syncthreads();

  for (int k0 = 0; k0 < K; k0 += 32){
    const int cur = (k0 >> 5) & 1;
    if (k0 + 32 < K) stage(k0 + 32, cur ^ 1);

    bf16x8 af[4], bfr[4];
    #pragma unroll
    for (int mf = 0; mf < 4; ++mf)
      af[mf]  = *(const bf16x8*)&As[cur][(wr*64 + mf*16 + (l & 15))*32 + (l >> 4)*8];
    #pragma unroll
    for (int nf = 0; nf < 4; ++nf)
      bfr[nf] = *(const bf16x8*)&Bs[cur][(wc*64 + nf*16 + (l & 15))*32 + (l >> 4)*8];
    #pragma unroll
    for (int mf = 0; mf < 4; ++mf)
      #pragma unroll
      for (int nf = 0; nf < 4; ++nf)
        acc[mf][nf] = __builtin_amdgcn_mfma_f32_16x16x32_bf16(af[mf], bfr[nf], acc[mf][nf], 0, 0, 0);

    __syncthreads();
  }

  #pragma unroll
  for (int nf = 0; nf < 4; ++nf){
    const int col = n0 + wc*64 + nf*16 + (l & 15);
    const float bv = bias[col];
    #pragma unroll
    for (int mf = 0; mf < 4; ++mf){
      #pragma unroll
      for (int r = 0; r < 4; ++r){
        const int row = m0 + wr*64 + mf*16 + (l >> 4)*4 + r;
        const float v = acc[mf][nf][r] + bv;
        if constexpr (BF16OUT) ((u16*)C)[(size_t)row * NC + col] = f2bf(v);
        else                   ((float*)C)[(size_t)row * NC + col] = v;
      }
    }
  }
}

// ---------------- causal flash attention: wave-autonomous, dual-stream, split-K ----
// grid = (32 bh, 32 qgrp), block 128 = 2 waves = 2 split-K halves of one 64-row
// q-group. Each wave: dual 32-q streams (lo/hi) sharing PRIVATELY-staged K/V
// (16 KiB dbuf per wave) -> own counted vmcnt orders DMA, ZERO barriers in the
// k-loop. R10 fix: prefetch unit index is kb + it + 1 (R9 dropped kb -> wave 1
// prefetched wave-0's k-range; absmax 0.084).
__global__ __launch_bounds__(128, 3) void k_attn(const u16* __restrict__ qkv,
                                                 u16* __restrict__ aout){
  __shared__ u16 smem[16384];   // 32 KiB: wave w at [w*8192]: K dbuf 2x2048 | V dbuf 2x2048 (u16)

  const int bh = blockIdx.x;
  const int b  = bh >> 4;
  const int h  = bh & 15;
  const int g  = 31 - (int)blockIdx.y;     // 64-row q-group
  const int tid = threadIdx.x;
  const int w = tid >> 6;                  // k-half (0 or 1)
  const int l = tid & 63;
  const int U  = g + 1;                    // units (32 k-rows) per half — uniform
  const int kb = w ? U : 0;                // my first unit
  const int q0lo = g*64, q0hi = g*64 + 32;
  const size_t base = (size_t)b * SEQ * QKVC + (size_t)h * 192;
  const float CEXP = 0.18033688011112042f; // 0.125 * log2(e)

  u16* const Kw = smem + w*8192;           // + cb*2048
  u16* const Vw = smem + w*8192 + 4096;    // + cb*2048

  // ---- per-lane private staging bases (XOR pre-swizzled K; inverse-subtile V)
  const int cgK = (l & 7) ^ ((l >> 3) & 7);
  const u16* const baseK = qkv + base + (size_t)(l >> 3) * QKVC + 64 + cgK*8;
  const int vk = ((l >> 5) << 2) | ((l >> 1) & 3);
  const int vd = (((l >> 3) & 3) << 4) | ((l & 1) << 3);
  const u16* const baseV = qkv + base + (size_t)vk * QKVC + 128 + vd;

  auto stage = [&](int u, int cb){         // 8 DMA ops, wave-private
    const u16* pk = baseK + (size_t)u * 32 * QKVC;
    const u16* pv = baseV + (size_t)u * 32 * QKVC;
    #pragma unroll
    for (int t = 0; t < 4; ++t){
      __builtin_amdgcn_global_load_lds(to_glob(pk + t*8*QKVC), to_lds(&Kw[cb*2048 + t*512]), 16, 0, 0);
      __builtin_amdgcn_global_load_lds(to_glob(pv + t*8*QKVC), to_lds(&Vw[cb*2048 + t*512]), 16, 0, 0);
    }
  };

  // Q B-frags for both streams: col=q=(l&31), k-dim d=(l>>5)*8 + dd*16 + j
  bf16x8 qfL[4], qfH[4];
  {
    const u16* qa = qkv + base + (size_t)(q0lo + (l & 31)) * QKVC + (l >> 5) * 8;
    const u16* qb = qkv + base + (size_t)(q0hi + (l & 31)) * QKVC + (l >> 5) * 8;
    #pragma unroll
    for (int dd = 0; dd < 4; ++dd){
      qfL[dd] = *(const bf16x8*)(qa + dd*16);
      qfH[dd] = *(const bf16x8*)(qb + dd*16);
    }
  }

  f32x16 oL0{}, oL1{}, oH0{}, oH1{};
  float mL = -1e30f, lsL = 0.f, mH = -1e30f, lsH = 0.f;

  stage(kb, 0);                            // prologue

  const u32 vbytes = lds_off(Vw) + (l & 15)*8 + ((l >> 4) & 1)*128 + (l >> 5)*1024;

  for (int it = 0; it < U; ++it){
    const int cb = it & 1;
    const int u  = kb + it;

    // prefetch next unit, then wait for CURRENT unit's 8 DMA (counted vmcnt, T4)
    if (it + 1 < U){
      stage(kb + it + 1, cb ^ 1);
      asm volatile("s_waitcnt vmcnt(8)" ::: "memory");
    } else {
      asm volatile("s_waitcnt vmcnt(0)" ::: "memory");
    }
    __builtin_amdgcn_sched_barrier(0);

    const bool loAct = (u*32 <= q0lo + 31);   // lo fully masked past its diagonal

    // ---- QK^T: shared K-frags, dual streams (8 MFMA, 4 ds_read_b128)
    f32x16 aL{}, aH{};
    const int r0 = l & 31;
    #pragma unroll
    for (int dd = 0; dd < 4; ++dd){
      const int c = dd*2 + (l >> 5);
      const bf16x8 kf = *(const bf16x8*)&Kw[cb*2048 + r0*64 + ((c ^ (r0 & 7)))*8];
      aL = MFMA32(kf, qfL[dd], aL);
      aH = MFMA32(kf, qfH[dd], aH);
    }

    // ---- causal masks (diagonal units only)
    if (loAct && u*32 + 31 > q0lo){
      const int qg = q0lo + (l & 31);
      #pragma unroll
      for (int r = 0; r < 16; ++r){
        const int kg = u*32 + (r & 3) + 8*(r >> 2) + 4*(l >> 5);
        if (kg > qg) aL[r] = -1e30f;
      }
    }
    if (u*32 + 31 > q0hi){
      const int qg = q0hi + (l & 31);
      #pragma unroll
      for (int r = 0; r < 16; ++r){
        const int kg = u*32 + (r & 3) + 8*(r >> 2) + 4*(l >> 5);
        if (kg > qg) aH[r] = -1e30f;
      }
    }

    // ---- row-max (both streams)
    float pmL = -1e30f, pmH = -1e30f;
    #pragma unroll
    for (int r = 0; r < 16; ++r){
      pmL = fmaxf(pmL, aL[r]);
      pmH = fmaxf(pmH, aH[r]);
    }
    pmL = fmaxf(pmL, __shfl(pmL, l ^ 32));
    pmH = fmaxf(pmH, __shfl(pmH, l ^ 32));

    // ---- issue all 8 tr_reads (shared); softmax below hides LDS latency
    s16x4 tr[8];
    {
      const u32 vb = vbytes + (cb ? 4096u : 0u);
      #pragma unroll
      for (int kk = 0; kk < 2; ++kk){
        asm volatile("ds_read_b64_tr_b16 %0, %4 offset:0\n\t"
                     "ds_read_b64_tr_b16 %1, %4 offset:512\n\t"
                     "ds_read_b64_tr_b16 %2, %4 offset:256\n\t"
                     "ds_read_b64_tr_b16 %3, %4 offset:768"
                     : "=&v"(tr[kk*4+0]), "=&v"(tr[kk*4+1]),
                       "=&v"(tr[kk*4+2]), "=&v"(tr[kk*4+3])
                     : "v"(vb + kk*2048));
      }
    }

    // ---- softmax both streams (T13 defer-max)
    if (loAct){
      if (__any(pmL > mL + 64.f)){
        const float mn = fmaxf(mL, pmL);
        const float corr = exp2f((mL - mn) * CEXP);
        mL = mn; lsL *= corr;
        #pragma unroll
        for (int r = 0; r < 16; ++r){
          const int row = (r & 3) + 8*(r >> 2) + 4*(l >> 5);
          const float cr = __shfl(corr, row | (l & 32));
          oL0[r] *= cr; oL1[r] *= cr;
        }
      }
      #pragma unroll
      for (int r = 0; r < 16; ++r){
        const float p = exp2f((aL[r] - mL) * CEXP);
        lsL += p; aL[r] = p;
      }
    }
    {
      if (__any(pmH > mH + 64.f)){
        const float mn = fmaxf(mH, pmH);
        const float corr = exp2f((mH - mn) * CEXP);
        mH = mn; lsH *= corr;
        #pragma unroll
        for (int r = 0; r < 16; ++r){
          const int row = (r & 3) + 8*(r >> 2) + 4*(l >> 5);
          const float cr = __shfl(corr, row | (l & 32));
          oH0[r] *= cr; oH1[r] *= cr;
        }
      }
      #pragma unroll
      for (int r = 0; r < 16; ++r){
        const float p = exp2f((aH[r] - mH) * CEXP);
        lsH += p; aH[r] = p;
      }
    }

    // ---- wait V once, PV both streams off shared tr regs
    asm volatile("s_waitcnt lgkmcnt(0)" ::: "memory");
    __builtin_amdgcn_sched_barrier(0);
    #pragma unroll
    for (int kk = 0; kk < 2; ++kk){
      union { s16x4 hh[2]; bf16x8 v; } b0, b1;
      b0.hh[0] = tr[kk*4+0]; b0.hh[1] = tr[kk*4+1];
      b1.hh[0] = tr[kk*4+2]; b1.hh[1] = tr[kk*4+3];
      const int o = kk * 8;
      if (loAct){
        const u32 x0 = pk2(aL[o+0], aL[o+1]);
        const u32 x1 = pk2(aL[o+2], aL[o+3]);
        const u32 y0 = pk2(aL[o+4], aL[o+5]);
        const u32 y1 = pk2(aL[o+6], aL[o+7]);
        const u32x2 r0v = __builtin_amdgcn_permlane32_swap(x0, y0, false, false);
        const u32x2 r1v = __builtin_amdgcn_permlane32_swap(x1, y1, false, false);
        union { u32 wd[4]; bf16x8 v; } af;
        af.wd[0] = r0v[0]; af.wd[1] = r1v[0]; af.wd[2] = r0v[1]; af.wd[3] = r1v[1];
        oL0 = MFMA32(af.v, b0.v, oL0);
        oL1 = MFMA32(af.v, b1.v, oL1);
      }
      {
        const u32 x0 = pk2(aH[o+0], aH[o+1]);
        const u32 x1 = pk2(aH[o+2], aH[o+3]);
        const u32 y0 = pk2(aH[o+4], aH[o+5]);
        const u32 y1 = pk2(aH[o+6], aH[o+7]);
        const u32x2 r0v = __builtin_amdgcn_permlane32_swap(x0, y0, false, false);
        const u32x2 r1v = __builtin_amdgcn_permlane32_swap(x1, y1, false, false);
        union { u32 wd[4]; bf16x8 v; } af;
        af.wd[0] = r0v[0]; af.wd[1] = r1v[0]; af.wd[2] = r0v[1]; af.wd[3] = r1v[1];
        oH0 = MFMA32(af.v, b0.v, oH0);
        oH1 = MFMA32(af.v, b1.v, oH1);
      }
    }
    // no barrier: staging is wave-private, ordered by this wave's own counters
  }

  // ---- cross-half merge: wave 1 publishes (O, m, l) via dead staging LDS
  lsL += __shfl(lsL, l ^ 32);
  lsH += __shfl(lsH, l ^ 32);
  __syncthreads();
  float*  const O1 = (float*)(smem + 8192);   // bytes [16384,32768): 4096 f32
  float4* const ML = (float4*)smem;           // bytes [0,1024)
  if (w == 1){
    #pragma unroll
    for (int r = 0; r < 16; ++r){
      O1[0*1024 + l*16 + r] = oL0[r];
      O1[1*1024 + l*16 + r] = oL1[r];
      O1[2*1024 + l*16 + r] = oH0[r];
      O1[3*1024 + l*16 + r] = oH1[r];
    }
    ML[l] = float4{mL, lsL, mH, lsH};
  }
  __syncthreads();

  if (w == 0){
    const float4 ml1 = ML[l];
    // lo stream
    {
      const float mm = fmaxf(mL, ml1.x);
      const float c0 = exp2f((mL - mm) * CEXP);
      const float c1 = exp2f((ml1.x - mm) * CEXP);
      const float lm = lsL*c0 + ml1.y*c1;
      const float a0q = c0 / lm, a1q = c1 / lm;
      #pragma unroll
      for (int r = 0; r < 16; ++r){
        const int row = (r & 3) + 8*(r >> 2) + 4*(l >> 5);
        const float f0 = __shfl(a0q, row | (l & 32));
        const float f1 = __shfl(a1q, row | (l & 32));
        u16* op = aout + (size_t)(b*SEQ + q0lo + row) * HIDDEN + h*64 + (l & 31);
        op[0]  = f2bf(oL0[r]*f0 + O1[0*1024 + l*16 + r]*f1);
        op[32] = f2bf(oL1[r]*f0 + O1[1*1024 + l*16 + r]*f1);
      }
    }
    // hi stream
    {
      const float mm = fmaxf(mH, ml1.z);
      const float c0 = exp2f((mH - mm) * CEXP);
      const float c1 = exp2f((ml1.z - mm) * CEXP);
      const float lm = lsH*c0 + ml1.w*c1;
      const float a0q = c0 / lm, a1q = c1 / lm;
      #pragma unroll
      for (int r = 0; r < 16; ++r){
        const int row = (r & 3) + 8*(r >> 2) + 4*(l >> 5);
        const float f0 = __shfl(a0q, row | (l & 32));
        const float f1 = __shfl(a1q, row | (l & 32));
        u16* op = aout + (size_t)(b*SEQ + q0hi + row) * HIDDEN + h*64 + (l & 31);
        op[0]  = f2bf(oH0[r]*f0 + O1[2*1024 + l*16 + r]*f1);
        op[32] = f2bf(oH1[r]*f0 + O1[3*1024 + l*16 + r]*f1);
      }
    }
  }
}

// ---------------- launch ----------------
extern "C" void kernel_launch(void* const* d_in, const int* in_sizes, int n_in,
                              void* d_out, int out_size, void* d_ws, size_t ws_size,
                              hipStream_t stream){
  const float* enc    = (const float*)d_in[0];
  const float* attn_w = (const float*)d_in[1];
  const float* attn_b = (const float*)d_in[2];
  const float* out_w  = (const float*)d_in[3];
  const float* out_b  = (const float*)d_in[4];

  char* ws = (char*)d_ws;
  u16* enc_bf = (u16*)(ws);
  u16* wa_bf  = (u16*)(ws + (size_t)( 8u << 20));
  u16* wo_bf  = (u16*)(ws + (size_t)(14u << 20));
  u16* qkv    = (u16*)(ws + (size_t)(16u << 20));
  u16* aout   = enc_bf;  // safe alias: attn runs strictly after GEMM1

  k_cvt3<<<dim3((CVT_N0+CVT_N1+CVT_N2 + 255)/256), 256, 0, stream>>>(
      enc, attn_w, out_w, enc_bf, wa_bf, wo_bf);

  k_gemm<QKVC,  true ><<<dim3(MROWS/128, QKVC/128),  256, 0, stream>>>(enc_bf, wa_bf, attn_b, qkv);
  k_attn<<<dim3(32, 32), 128, 0, stream>>>(qkv, aout);
  k_gemm<HIDDEN, false><<<dim3(MROWS/128, HIDDEN/128), 256, 0, stream>>>(aout, wo_bf, out_b, d_out);
}

// Round 11
// 117.134 us; speedup vs baseline: 1.2118x; 1.2118x over previous
//
#include <hip/hip_runtime.h>
#include <hip/hip_bf16.h>
#include <stdint.h>

#define HIDDEN 1024
#define NHEADS 16
#define DHEAD  64
#define BATCH  2
#define SEQ    2048
#define MROWS  (BATCH*SEQ)   // 4096
#define QKVC   (3*HIDDEN)    // 3072

typedef unsigned short u16;
typedef unsigned int   u32;
typedef __bf16 bf16x8 __attribute__((ext_vector_type(8)));
typedef __bf16 bf16x2 __attribute__((ext_vector_type(2)));
typedef float  f32x4  __attribute__((ext_vector_type(4)));
typedef float  f32x16 __attribute__((ext_vector_type(16)));
typedef short  s16x4  __attribute__((ext_vector_type(4)));
typedef u16    u16x8  __attribute__((ext_vector_type(8)));
typedef u32    u32x2  __attribute__((ext_vector_type(2)));

typedef const __attribute__((address_space(1))) void gvoid_t;
typedef       __attribute__((address_space(3))) void lvoid_t;

__device__ __forceinline__ gvoid_t* to_glob(const void* p){
  return (gvoid_t*)(uintptr_t)p;
}
__device__ __forceinline__ lvoid_t* to_lds(void* p){
  return (lvoid_t*)(uintptr_t)p;
}
__device__ __forceinline__ u32 lds_off(const void* p){
  return (u32)(uintptr_t)p;
}

// native f32->bf16 (hardware RNE cvt on gfx950)
__device__ __forceinline__ u16 f2bf(float x){
  __bf16 h = (__bf16)x;
  return __builtin_bit_cast(u16, h);
}
// packed f32x2 -> bf16x2 word (compiler emits v_cvt_pk_bf16_f32)
__device__ __forceinline__ u32 pk2(float a, float b){
  bf16x2 t = { (__bf16)a, (__bf16)b };
  return __builtin_bit_cast(u32, t);
}

#define MFMA32(a, b, c) __builtin_amdgcn_mfma_f32_32x32x16_bf16(a, b, c, 0, 0, 0)

// ---------------- fp32 -> bf16 conversion, all 3 inputs in one launch ----------------
#define CVT_N0 1048576   // enc      (4M f32 / 4)
#define CVT_N1  786432   // attn_w   (3M f32 / 4)
#define CVT_N2  262144   // out_w    (1M f32 / 4)
__global__ __launch_bounds__(256) void k_cvt3(const float* __restrict__ e,
                                              const float* __restrict__ wa,
                                              const float* __restrict__ wo,
                                              u16* __restrict__ eb,
                                              u16* __restrict__ wab,
                                              u16* __restrict__ wob){
  int i = blockIdx.x * 256 + threadIdx.x;
  const float* src; u16* dst;
  if (i < CVT_N0){ src = e; dst = eb; }
  else if (i < CVT_N0 + CVT_N1){ i -= CVT_N0; src = wa; dst = wab; }
  else if (i < CVT_N0 + CVT_N1 + CVT_N2){ i -= CVT_N0 + CVT_N1; src = wo; dst = wob; }
  else return;
  const float4 v = reinterpret_cast<const float4*>(src)[i];
  ushort4 o;
  o.x = f2bf(v.x); o.y = f2bf(v.y); o.z = f2bf(v.z); o.w = f2bf(v.w);
  reinterpret_cast<ushort4*>(dst)[i] = o;
}

// ---------------- bf16 GEMM, C = A * B^T + bias (unchanged from R6) ----------------
template<int NC, bool BF16OUT>
__global__ __launch_bounds__(256) void k_gemm(const u16* __restrict__ A,
                                              const u16* __restrict__ B,
                                              const float* __restrict__ bias,
                                              void* __restrict__ C){
  constexpr int K = HIDDEN;
  __shared__ u16 As[2][128*32];
  __shared__ u16 Bs[2][128*32];
  const int m0 = blockIdx.x * 128;
  const int n0 = blockIdx.y * 128;
  const int tid = threadIdx.x;
  const int w = tid >> 6, l = tid & 63;
  const int wr = w >> 1, wc = w & 1;

  const f32x4 fz = {0.f, 0.f, 0.f, 0.f};
  f32x4 acc[4][4];
  #pragma unroll
  for (int i = 0; i < 4; ++i)
    #pragma unroll
    for (int j = 0; j < 4; ++j) acc[i][j] = fz;

  const u16* ap = A + (size_t)(m0 + (tid >> 2)) * K + (tid & 3) * 8;
  const u16* bp = B + (size_t)(n0 + (tid >> 2)) * K + (tid & 3) * 8;

  auto stage = [&](int k0, int buf){
    __builtin_amdgcn_global_load_lds(to_glob(ap + k0),        to_lds(&As[buf][w*512]),        16, 0, 0);
    __builtin_amdgcn_global_load_lds(to_glob(ap + 64*K + k0), to_lds(&As[buf][2048 + w*512]), 16, 0, 0);
    __builtin_amdgcn_global_load_lds(to_glob(bp + k0),        to_lds(&Bs[buf][w*512]),        16, 0, 0);
    __builtin_amdgcn_global_load_lds(to_glob(bp + 64*K + k0), to_lds(&Bs[buf][2048 + w*512]), 16, 0, 0);
  };

  stage(0, 0);
  __syncthreads();

  for (int k0 = 0; k0 < K; k0 += 32){
    const int cur = (k0 >> 5) & 1;
    if (k0 + 32 < K) stage(k0 + 32, cur ^ 1);

    bf16x8 af[4], bfr[4];
    #pragma unroll
    for (int mf = 0; mf < 4; ++mf)
      af[mf]  = *(const bf16x8*)&As[cur][(wr*64 + mf*16 + (l & 15))*32 + (l >> 4)*8];
    #pragma unroll
    for (int nf = 0; nf < 4; ++nf)
      bfr[nf] = *(const bf16x8*)&Bs[cur][(wc*64 + nf*16 + (l & 15))*32 + (l >> 4)*8];
    #pragma unroll
    for (int mf = 0; mf < 4; ++mf)
      #pragma unroll
      for (int nf = 0; nf < 4; ++nf)
        acc[mf][nf] = __builtin_amdgcn_mfma_f32_16x16x32_bf16(af[mf], bfr[nf], acc[mf][nf], 0, 0, 0);

    __syncthreads();
  }

  #pragma unroll
  for (int nf = 0; nf < 4; ++nf){
    const int col = n0 + wc*64 + nf*16 + (l & 15);
    const float bv = bias[col];
    #pragma unroll
    for (int mf = 0; mf < 4; ++mf){
      #pragma unroll
      for (int r = 0; r < 4; ++r){
        const int row = m0 + wr*64 + mf*16 + (l >> 4)*4 + r;
        const float v = acc[mf][nf][r] + bv;
        if constexpr (BF16OUT) ((u16*)C)[(size_t)row * NC + col] = f2bf(v);
        else                   ((float*)C)[(size_t)row * NC + col] = v;
      }
    }
  }
}

// ---------------- causal flash attention: R8 engine + triple-buffer counted-vmcnt ----
// grid = (32 bh, 32 qt LPT), block 256 = 4 waves (hr = k-half, wr = q-half).
// R8 structure (45.8us verified) with the per-unit __syncthreads (full
// vmcnt0+lgkm0 drain) replaced by: s_waitcnt vmcnt(4) [own 4 staging DMAs of
// current unit landed] -> raw s_barrier [cross-wave visibility, no drain] ->
// stage(it+2) [distance-2 prefetch] -> compute. Triple-buffered K/V per half
// (WAR-safe: readers of buf[(it+2)%3] all finished before barrier(it)).
// LDS 48 KiB -> 3 blocks/CU; register profile identical to R8 (no spill).
__global__ __launch_bounds__(256, 4) void k_attn(const u16* __restrict__ qkv,
                                                 u16* __restrict__ aout){
  __shared__ u16 smem[24576];   // 48 KiB: half hr at [hr*12288]: K 3x2048 | V 3x2048 (u16)

  const int bh = blockIdx.x;
  const int b  = bh >> 4;
  const int h  = bh & 15;
  const int qt = 31 - blockIdx.y;          // LPT: longest blocks first
  const int tid = threadIdx.x;
  const int l  = tid & 63;
  const int w  = tid >> 6;
  const int hr = w >> 1;                   // k-half (0 or 1)
  const int wr = w & 1;                    // q-row half within tile
  const int t128 = tid & 127;
  const int lw = t128 >> 6;                // wave-within-half
  const int U  = qt + 1;                   // 32-k units per half (uniform)
  const int kb = hr ? U : 0;               // my first unit
  const int q0 = qt*64 + wr*32;            // this wave's 32 q-rows
  const size_t base = (size_t)b * SEQ * QKVC + (size_t)h * 192;
  const float CEXP = 0.18033688011112042f; // 0.125 * log2(e)

  u16* const Kreg = smem + hr*12288;          // + cb*2048 (u16), cb in {0,1,2}
  u16* const Vreg = smem + hr*12288 + 6144;   // + cb*2048 (u16)

  // ---- per-lane staging source bases (XOR pre-swizzled K; inverse-subtile V)
  const int cgK = (t128 & 7) ^ ((t128 >> 3) & 7);
  const u16* const baseK = qkv + base + (size_t)(t128 >> 3) * QKVC + 64 + cgK * 8;
  const int vk = ((t128 >> 5) << 2) | ((t128 >> 1) & 3);
  const int vd = (((t128 >> 3) & 3) << 4) | ((t128 & 1) << 3);
  const u16* const baseV = qkv + base + (size_t)vk * QKVC + 128 + vd;

  auto stage = [&](int u, int cb){   // 4 vmem instrs per wave (2 K + 2 V)
    const u16* pk = baseK + (size_t)u * 32 * QKVC;
    const u16* pv = baseV + (size_t)u * 32 * QKVC;
    #pragma unroll
    for (int t = 0; t < 2; ++t){
      __builtin_amdgcn_global_load_lds(to_glob(pk + t*16*QKVC),
                                       to_lds(&Kreg[cb*2048 + t*1024 + lw*512]), 16, 0, 0);
      __builtin_amdgcn_global_load_lds(to_glob(pv + t*16*QKVC),
                                       to_lds(&Vreg[cb*2048 + t*1024 + lw*512]), 16, 0, 0);
    }
  };

  // Q B-frags: col=q=(l&31), k-dim=d=(l>>5)*8 + dd*16 + j
  bf16x8 qf[4];
  {
    const u16* qp = qkv + base + (size_t)(q0 + (l & 31)) * QKVC + (l >> 5) * 8;
    #pragma unroll
    for (int dd = 0; dd < 4; ++dd) qf[dd] = *(const bf16x8*)(qp + dd*16);
  }

  f32x16 o0{}, o1{};              // O[q=row(r)][d=(l&31)+{0,32}]
  float m = -1e30f, lsum = 0.f;   // per-lane (q = l&31, own k-rows)

  // prologue: distance-2 prefetch (dummy re-stage of unit kb when U==1 keeps
  // the vmcnt invariant without OOB; buf1 is then never read)
  stage(kb, 0);
  stage(kb + (U > 1 ? 1 : 0), 1);

  const u32 vbytes = lds_off(Vreg) + (l & 15)*8 + ((l >> 4) & 1)*128 + (l >> 5)*1024;

  int cb = 0;                     // = it % 3
  for (int it = 0; it < U; ++it){
    const int u = kb + it;

    // own 4 staging DMAs of unit `it` landed; then align waves (NO drain)
    asm volatile("s_waitcnt vmcnt(4)" ::: "memory");
    __builtin_amdgcn_sched_barrier(0);
    __builtin_amdgcn_s_barrier();
    __builtin_amdgcn_sched_barrier(0);

    // distance-2 prefetch into buf[(it+2)%3] (readers all done per barrier)
    if (it + 2 < U) stage(kb + it + 2, (cb == 0) ? 2 : cb - 1);

    // ---- QK^T: S^T[k 0..31][q], 4 MFMA
    f32x16 a0{};
    const int r0 = l & 31;
    #pragma unroll
    for (int dd = 0; dd < 4; ++dd){
      const int c = dd*2 + (l >> 5);
      const bf16x8 k0 = *(const bf16x8*)&Kreg[cb*2048 + r0*64 + ((c ^ (r0 & 7)))*8];
      a0 = MFMA32(k0, qf[dd], a0);
    }

    // ---- causal mask (units reaching past the wave's first q-row)
    if (u*32 + 31 > q0){
      const int qg = q0 + (l & 31);
      #pragma unroll
      for (int r = 0; r < 16; ++r){
        const int kg = u*32 + (r & 3) + 8*(r >> 2) + 4*(l >> 5);
        if (kg > qg) a0[r] = -1e30f;
      }
    }

    // ---- row-max
    float pm = -1e30f;
    #pragma unroll
    for (int r = 0; r < 16; ++r) pm = fmaxf(pm, a0[r]);
    pm = fmaxf(pm, __shfl(pm, l ^ 32));

    // ---- issue all 8 tr_reads; softmax below hides LDS latency
    s16x4 tr[8];
    {
      const u32 vb = vbytes + (u32)cb * 4096u;
      #pragma unroll
      for (int kk = 0; kk < 2; ++kk){
        asm volatile("ds_read_b64_tr_b16 %0, %4 offset:0\n\t"
                     "ds_read_b64_tr_b16 %1, %4 offset:512\n\t"
                     "ds_read_b64_tr_b16 %2, %4 offset:256\n\t"
                     "ds_read_b64_tr_b16 %3, %4 offset:768"
                     : "=&v"(tr[kk*4+0]), "=&v"(tr[kk*4+1]),
                       "=&v"(tr[kk*4+2]), "=&v"(tr[kk*4+3])
                     : "v"(vb + kk*2048));
      }
    }

    if (__any(pm > m + 64.f)){            // T13 defer-max
      const float mn = fmaxf(m, pm);
      const float corr = exp2f((m - mn) * CEXP);
      m = mn;
      lsum *= corr;
      #pragma unroll
      for (int r = 0; r < 16; ++r){
        const int row = (r & 3) + 8*(r >> 2) + 4*(l >> 5);
        const float cr = __shfl(corr, row | (l & 32));
        o0[r] *= cr; o1[r] *= cr;
      }
    }
    #pragma unroll
    for (int r = 0; r < 16; ++r){
      const float p = exp2f((a0[r] - m) * CEXP);
      lsum += p;
      a0[r] = p;
    }

    // ---- wait V once, then PV: A-frag via cvt_pk + permlane32_swap
    asm volatile("s_waitcnt lgkmcnt(0)" ::: "memory");
    __builtin_amdgcn_sched_barrier(0);
    #pragma unroll
    for (int kk = 0; kk < 2; ++kk){
      const int o = kk * 8;
      const u32 x0 = pk2(a0[o+0], a0[o+1]);
      const u32 x1 = pk2(a0[o+2], a0[o+3]);
      const u32 y0 = pk2(a0[o+4], a0[o+5]);
      const u32 y1 = pk2(a0[o+6], a0[o+7]);
      const u32x2 r0v = __builtin_amdgcn_permlane32_swap(x0, y0, false, false);
      const u32x2 r1v = __builtin_amdgcn_permlane32_swap(x1, y1, false, false);
      union { u32 wd[4]; bf16x8 v; } af;
      af.wd[0] = r0v[0]; af.wd[1] = r1v[0]; af.wd[2] = r0v[1]; af.wd[3] = r1v[1];
      union { s16x4 hh[2]; bf16x8 v; } b0, b1;
      b0.hh[0] = tr[kk*4+0]; b0.hh[1] = tr[kk*4+1];
      b1.hh[0] = tr[kk*4+2]; b1.hh[1] = tr[kk*4+3];
      o0 = MFMA32(af.v, b0.v, o0);
      o1 = MFMA32(af.v, b1.v, o1);
    }

    cb = (cb == 2) ? 0 : cb + 1;
  }

  // ---- cross-half merge (once): staging LDS is dead after full drain
  lsum += __shfl(lsum, l ^ 32);             // combine lane k-halves (same q)
  __syncthreads();                          // drains all DMA + aligns block
  float* const Osh  = (float*)smem;                         // 16 KB
  float2* const MLsh = (float2*)((char*)smem + 16384);      // 1 KB

  if (hr == 1){
    #pragma unroll
    for (int r = 0; r < 16; ++r){
      Osh[wr*2048 + l*32 + r]      = o0[r];
      Osh[wr*2048 + l*32 + 16 + r] = o1[r];
    }
    MLsh[wr*64 + l] = float2{m, lsum};
  }
  __syncthreads();

  if (hr == 0){
    const float2 ml1 = MLsh[wr*64 + l];
    const float mm = fmaxf(m, ml1.x);
    const float c0 = exp2f((m - mm) * CEXP);
    const float c1 = exp2f((ml1.x - mm) * CEXP);
    const float lm = lsum*c0 + ml1.y*c1;    // >0 always (half-0 non-empty)
    const float a0q = c0 / lm;
    const float a1q = c1 / lm;
    #pragma unroll
    for (int r = 0; r < 16; ++r){
      const int row = (r & 3) + 8*(r >> 2) + 4*(l >> 5);
      const float f0 = __shfl(a0q, row | (l & 32));
      const float f1 = __shfl(a1q, row | (l & 32));
      const int qg = q0 + row;
      u16* op = aout + (size_t)(b*SEQ + qg) * HIDDEN + h*64 + (l & 31);
      op[0]  = f2bf(o0[r]*f0 + Osh[wr*2048 + l*32 + r]*f1);
      op[32] = f2bf(o1[r]*f0 + Osh[wr*2048 + l*32 + 16 + r]*f1);
    }
  }
}

// ---------------- launch ----------------
extern "C" void kernel_launch(void* const* d_in, const int* in_sizes, int n_in,
                              void* d_out, int out_size, void* d_ws, size_t ws_size,
                              hipStream_t stream){
  const float* enc    = (const float*)d_in[0];
  const float* attn_w = (const float*)d_in[1];
  const float* attn_b = (const float*)d_in[2];
  const float* out_w  = (const float*)d_in[3];
  const float* out_b  = (const float*)d_in[4];

  char* ws = (char*)d_ws;
  u16* enc_bf = (u16*)(ws);
  u16* wa_bf  = (u16*)(ws + (size_t)( 8u << 20));
  u16* wo_bf  = (u16*)(ws + (size_t)(14u << 20));
  u16* qkv    = (u16*)(ws + (size_t)(16u << 20));
  u16* aout   = enc_bf;  // safe alias: attn runs strictly after GEMM1

  k_cvt3<<<dim3((CVT_N0+CVT_N1+CVT_N2 + 255)/256), 256, 0, stream>>>(
      enc, attn_w, out_w, enc_bf, wa_bf, wo_bf);

  k_gemm<QKVC,  true ><<<dim3(MROWS/128, QKVC/128),  256, 0, stream>>>(enc_bf, wa_bf, attn_b, qkv);
  k_attn<<<dim3(32, 32), 256, 0, stream>>>(qkv, aout);
  k_gemm<HIDDEN, false><<<dim3(MROWS/128, HIDDEN/128), 256, 0, stream>>>(aout, wo_bf, out_b, d_out);
}

// Round 12
// 105.602 us; speedup vs baseline: 1.3442x; 1.1092x over previous
//
#include <hip/hip_runtime.h>
#include <hip/hip_bf16.h>
#include <stdint.h>

#define HIDDEN 1024
#define NHEADS 16
#define DHEAD  64
#define BATCH  2
#define SEQ    2048
#define MROWS  (BATCH*SEQ)   // 4096
#define QKVC   (3*HIDDEN)    // 3072

typedef unsigned short u16;
typedef unsigned int   u32;
typedef __bf16 bf16x8 __attribute__((ext_vector_type(8)));
typedef __bf16 bf16x2 __attribute__((ext_vector_type(2)));
typedef float  f32x4  __attribute__((ext_vector_type(4)));
typedef float  f32x16 __attribute__((ext_vector_type(16)));
typedef short  s16x4  __attribute__((ext_vector_type(4)));
typedef u16    u16x8  __attribute__((ext_vector_type(8)));
typedef u32    u32x2  __attribute__((ext_vector_type(2)));

typedef const __attribute__((address_space(1))) void gvoid_t;
typedef       __attribute__((address_space(3))) void lvoid_t;

__device__ __forceinline__ gvoid_t* to_glob(const void* p){
  return (gvoid_t*)(uintptr_t)p;
}
__device__ __forceinline__ lvoid_t* to_lds(void* p){
  return (lvoid_t*)(uintptr_t)p;
}
__device__ __forceinline__ u32 lds_off(const void* p){
  return (u32)(uintptr_t)p;
}

// native f32->bf16 (hardware RNE cvt on gfx950)
__device__ __forceinline__ u16 f2bf(float x){
  __bf16 h = (__bf16)x;
  return __builtin_bit_cast(u16, h);
}
// packed f32x2 -> bf16x2 word (compiler emits v_cvt_pk_bf16_f32)
__device__ __forceinline__ u32 pk2(float a, float b){
  bf16x2 t = { (__bf16)a, (__bf16)b };
  return __builtin_bit_cast(u32, t);
}

#define MFMA32(a, b, c) __builtin_amdgcn_mfma_f32_32x32x16_bf16(a, b, c, 0, 0, 0)

// ---------------- fp32 -> bf16 conversion, all 3 inputs in one launch ----------------
#define CVT_N0 1048576   // enc      (4M f32 / 4)
#define CVT_N1  786432   // attn_w   (3M f32 / 4)
#define CVT_N2  262144   // out_w    (1M f32 / 4)
__global__ __launch_bounds__(256) void k_cvt3(const float* __restrict__ e,
                                              const float* __restrict__ wa,
                                              const float* __restrict__ wo,
                                              u16* __restrict__ eb,
                                              u16* __restrict__ wab,
                                              u16* __restrict__ wob){
  int i = blockIdx.x * 256 + threadIdx.x;
  const float* src; u16* dst;
  if (i < CVT_N0){ src = e; dst = eb; }
  else if (i < CVT_N0 + CVT_N1){ i -= CVT_N0; src = wa; dst = wab; }
  else if (i < CVT_N0 + CVT_N1 + CVT_N2){ i -= CVT_N0 + CVT_N1; src = wo; dst = wob; }
  else return;
  const float4 v = reinterpret_cast<const float4*>(src)[i];
  ushort4 o;
  o.x = f2bf(v.x); o.y = f2bf(v.y); o.z = f2bf(v.z); o.w = f2bf(v.w);
  reinterpret_cast<ushort4*>(dst)[i] = o;
}

// ---------------- bf16 GEMM, C = A * B^T + bias (unchanged from R6) ----------------
template<int NC, bool BF16OUT>
__global__ __launch_bounds__(256) void k_gemm(const u16* __restrict__ A,
                                              const u16* __restrict__ B,
                                              const float* __restrict__ bias,
                                              void* __restrict__ C){
  constexpr int K = HIDDEN;
  __shared__ u16 As[2][128*32];
  __shared__ u16 Bs[2][128*32];
  const int m0 = blockIdx.x * 128;
  const int n0 = blockIdx.y * 128;
  const int tid = threadIdx.x;
  const int w = tid >> 6, l = tid & 63;
  const int wr = w >> 1, wc = w & 1;

  const f32x4 fz = {0.f, 0.f, 0.f, 0.f};
  f32x4 acc[4][4];
  #pragma unroll
  for (int i = 0; i < 4; ++i)
    #pragma unroll
    for (int j = 0; j < 4; ++j) acc[i][j] = fz;

  const u16* ap = A + (size_t)(m0 + (tid >> 2)) * K + (tid & 3) * 8;
  const u16* bp = B + (size_t)(n0 + (tid >> 2)) * K + (tid & 3) * 8;

  auto stage = [&](int k0, int buf){
    __builtin_amdgcn_global_load_lds(to_glob(ap + k0),        to_lds(&As[buf][w*512]),        16, 0, 0);
    __builtin_amdgcn_global_load_lds(to_glob(ap + 64*K + k0), to_lds(&As[buf][2048 + w*512]), 16, 0, 0);
    __builtin_amdgcn_global_load_lds(to_glob(bp + k0),        to_lds(&Bs[buf][w*512]),        16, 0, 0);
    __builtin_amdgcn_global_load_lds(to_glob(bp + 64*K + k0), to_lds(&Bs[buf][2048 + w*512]), 16, 0, 0);
  };

  stage(0, 0);
  __syncthreads();

  for (int k0 = 0; k0 < K; k0 += 32){
    const int cur = (k0 >> 5) & 1;
    if (k0 + 32 < K) stage(k0 + 32, cur ^ 1);

    bf16x8 af[4], bfr[4];
    #pragma unroll
    for (int mf = 0; mf < 4; ++mf)
      af[mf]  = *(const bf16x8*)&As[cur][(wr*64 + mf*16 + (l & 15))*32 + (l >> 4)*8];
    #pragma unroll
    for (int nf = 0; nf < 4; ++nf)
      bfr[nf] = *(const bf16x8*)&Bs[cur][(wc*64 + nf*16 + (l & 15))*32 + (l >> 4)*8];
    #pragma unroll
    for (int mf = 0; mf < 4; ++mf)
      #pragma unroll
      for (int nf = 0; nf < 4; ++nf)
        acc[mf][nf] = __builtin_amdgcn_mfma_f32_16x16x32_bf16(af[mf], bfr[nf], acc[mf][nf], 0, 0, 0);

    __syncthreads();
  }

  #pragma unroll
  for (int nf = 0; nf < 4; ++nf){
    const int col = n0 + wc*64 + nf*16 + (l & 15);
    const float bv = bias[col];
    #pragma unroll
    for (int mf = 0; mf < 4; ++mf){
      #pragma unroll
      for (int r = 0; r < 4; ++r){
        const int row = m0 + wr*64 + mf*16 + (l >> 4)*4 + r;
        const float v = acc[mf][nf][r] + bv;
        if constexpr (BF16OUT) ((u16*)C)[(size_t)row * NC + col] = f2bf(v);
        else                   ((float*)C)[(size_t)row * NC + col] = v;
      }
    }
  }
}

// ---------------- causal flash attention: counted-vmcnt, K 3-buf / V 2-buf ----
// grid = (32 bh, 32 qt LPT), block 256 = 4 waves (hr = k-half, wr = q-half).
// R11 sync scheme (own-vmcnt wait BEFORE raw s_barrier, no drain) with
// asymmetric buffering to fit 40 KiB -> 4 blocks/CU (R11's 48K = 3 was the
// regression): K triple-buffered (distance-2), V double-buffered (distance-1).
// vmcnt ledger (per wave, 2 DMA per stage call): prologue K0,V0,K1; each iter
// waits vmcnt(2) [= K(it),V(it) landed, K(it+1) in flight], then issues
// V(it+1) BEFORE K(it+2) — order is load-bearing for the invariant.
// Tail prefetches clamp to kmax (valid redundant loads) to keep the count.
__global__ __launch_bounds__(256, 4) void k_attn(const u16* __restrict__ qkv,
                                                 u16* __restrict__ aout){
  __shared__ u16 smem[20480];   // 40 KiB: half hr at [hr*10240]: K 3x2048 | V 2x2048 (u16)

  const int bh = blockIdx.x;
  const int b  = bh >> 4;
  const int h  = bh & 15;
  const int qt = 31 - blockIdx.y;          // LPT: longest blocks first
  const int tid = threadIdx.x;
  const int l  = tid & 63;
  const int w  = tid >> 6;
  const int hr = w >> 1;                   // k-half (0 or 1)
  const int wr = w & 1;                    // q-row half within tile
  const int t128 = tid & 127;
  const int lw = t128 >> 6;                // wave-within-half
  const int U  = qt + 1;                   // 32-k units per half (uniform)
  const int kb = hr ? U : 0;               // my first unit
  const int kmax = kb + U - 1;             // clamp target for tail prefetch
  const int q0 = qt*64 + wr*32;            // this wave's 32 q-rows
  const size_t base = (size_t)b * SEQ * QKVC + (size_t)h * 192;
  const float CEXP = 0.18033688011112042f; // 0.125 * log2(e)

  u16* const Kreg = smem + hr*10240;          // + cb*2048 (u16), cb in {0,1,2}
  u16* const Vreg = smem + hr*10240 + 6144;   // + vb*2048 (u16), vb in {0,1}

  // ---- per-lane staging source bases (XOR pre-swizzled K; inverse-subtile V)
  const int cgK = (t128 & 7) ^ ((t128 >> 3) & 7);
  const u16* const baseK = qkv + base + (size_t)(t128 >> 3) * QKVC + 64 + cgK * 8;
  const int vk = ((t128 >> 5) << 2) | ((t128 >> 1) & 3);
  const int vd = (((t128 >> 3) & 3) << 4) | ((t128 & 1) << 3);
  const u16* const baseV = qkv + base + (size_t)vk * QKVC + 128 + vd;

  auto stageK = [&](int u, int cb){   // 2 vmem instrs per wave
    const u16* pk = baseK + (size_t)u * 32 * QKVC;
    #pragma unroll
    for (int t = 0; t < 2; ++t)
      __builtin_amdgcn_global_load_lds(to_glob(pk + t*16*QKVC),
                                       to_lds(&Kreg[cb*2048 + t*1024 + lw*512]), 16, 0, 0);
  };
  auto stageV = [&](int u, int vb){   // 2 vmem instrs per wave
    const u16* pv = baseV + (size_t)u * 32 * QKVC;
    #pragma unroll
    for (int t = 0; t < 2; ++t)
      __builtin_amdgcn_global_load_lds(to_glob(pv + t*16*QKVC),
                                       to_lds(&Vreg[vb*2048 + t*1024 + lw*512]), 16, 0, 0);
  };

  // Q B-frags: col=q=(l&31), k-dim=d=(l>>5)*8 + dd*16 + j
  bf16x8 qf[4];
  {
    const u16* qp = qkv + base + (size_t)(q0 + (l & 31)) * QKVC + (l >> 5) * 8;
    #pragma unroll
    for (int dd = 0; dd < 4; ++dd) qf[dd] = *(const bf16x8*)(qp + dd*16);
  }

  f32x16 o0{}, o1{};              // O[q=row(r)][d=(l&31)+{0,32}]
  float m = -1e30f, lsum = 0.f;   // per-lane (q = l&31, own k-rows)

  // prologue ledger: K0, V0, K1 (6 ops outstanding; qf loads ahead of them)
  stageK(kb, 0);
  stageV(kb, 0);
  stageK(kb + (U > 1 ? 1 : 0), 1);

  const u32 vbytes = lds_off(Vreg) + (l & 15)*8 + ((l >> 4) & 1)*128 + (l >> 5)*1024;

  int cb3 = 0;                    // it % 3 (K buffer)
  int vb2 = 0;                    // it % 2 (V buffer)
  for (int it = 0; it < U; ++it){
    const int u = kb + it;

    // own K(it)+V(it) landed (K(it+1) stays in flight); then align waves, NO drain
    asm volatile("s_waitcnt vmcnt(2)" ::: "memory");
    __builtin_amdgcn_sched_barrier(0);
    __builtin_amdgcn_s_barrier();
    __builtin_amdgcn_sched_barrier(0);

    // V before K (keeps the two unwaited ops == next-K); clamp at tail
    stageV(u + 1 > kmax ? kmax : u + 1, vb2 ^ 1);
    stageK(u + 2 > kmax ? kmax : u + 2, cb3 == 0 ? 2 : cb3 - 1);

    // ---- QK^T: S^T[k 0..31][q], 4 MFMA
    f32x16 a0{};
    const int r0 = l & 31;
    #pragma unroll
    for (int dd = 0; dd < 4; ++dd){
      const int c = dd*2 + (l >> 5);
      const bf16x8 k0 = *(const bf16x8*)&Kreg[cb3*2048 + r0*64 + ((c ^ (r0 & 7)))*8];
      a0 = MFMA32(k0, qf[dd], a0);
    }

    // ---- causal mask (units reaching past the wave's first q-row)
    if (u*32 + 31 > q0){
      const int qg = q0 + (l & 31);
      #pragma unroll
      for (int r = 0; r < 16; ++r){
        const int kg = u*32 + (r & 3) + 8*(r >> 2) + 4*(l >> 5);
        if (kg > qg) a0[r] = -1e30f;
      }
    }

    // ---- row-max
    float pm = -1e30f;
    #pragma unroll
    for (int r = 0; r < 16; ++r) pm = fmaxf(pm, a0[r]);
    pm = fmaxf(pm, __shfl(pm, l ^ 32));

    // ---- issue all 8 tr_reads; softmax below hides LDS latency
    s16x4 tr[8];
    {
      const u32 vb = vbytes + (u32)vb2 * 4096u;
      #pragma unroll
      for (int kk = 0; kk < 2; ++kk){
        asm volatile("ds_read_b64_tr_b16 %0, %4 offset:0\n\t"
                     "ds_read_b64_tr_b16 %1, %4 offset:512\n\t"
                     "ds_read_b64_tr_b16 %2, %4 offset:256\n\t"
                     "ds_read_b64_tr_b16 %3, %4 offset:768"
                     : "=&v"(tr[kk*4+0]), "=&v"(tr[kk*4+1]),
                       "=&v"(tr[kk*4+2]), "=&v"(tr[kk*4+3])
                     : "v"(vb + kk*2048));
      }
    }

    if (__any(pm > m + 64.f)){            // T13 defer-max
      const float mn = fmaxf(m, pm);
      const float corr = exp2f((m - mn) * CEXP);
      m = mn;
      lsum *= corr;
      #pragma unroll
      for (int r = 0; r < 16; ++r){
        const int row = (r & 3) + 8*(r >> 2) + 4*(l >> 5);
        const float cr = __shfl(corr, row | (l & 32));
        o0[r] *= cr; o1[r] *= cr;
      }
    }
    #pragma unroll
    for (int r = 0; r < 16; ++r){
      const float p = exp2f((a0[r] - m) * CEXP);
      lsum += p;
      a0[r] = p;
    }

    // ---- wait V once, then PV: A-frag via cvt_pk + permlane32_swap
    asm volatile("s_waitcnt lgkmcnt(0)" ::: "memory");
    __builtin_amdgcn_sched_barrier(0);
    #pragma unroll
    for (int kk = 0; kk < 2; ++kk){
      const int o = kk * 8;
      const u32 x0 = pk2(a0[o+0], a0[o+1]);
      const u32 x1 = pk2(a0[o+2], a0[o+3]);
      const u32 y0 = pk2(a0[o+4], a0[o+5]);
      const u32 y1 = pk2(a0[o+6], a0[o+7]);
      const u32x2 r0v = __builtin_amdgcn_permlane32_swap(x0, y0, false, false);
      const u32x2 r1v = __builtin_amdgcn_permlane32_swap(x1, y1, false, false);
      union { u32 wd[4]; bf16x8 v; } af;
      af.wd[0] = r0v[0]; af.wd[1] = r1v[0]; af.wd[2] = r0v[1]; af.wd[3] = r1v[1];
      union { s16x4 hh[2]; bf16x8 v; } b0, b1;
      b0.hh[0] = tr[kk*4+0]; b0.hh[1] = tr[kk*4+1];
      b1.hh[0] = tr[kk*4+2]; b1.hh[1] = tr[kk*4+3];
      o0 = MFMA32(af.v, b0.v, o0);
      o1 = MFMA32(af.v, b1.v, o1);
    }

    cb3 = (cb3 == 2) ? 0 : cb3 + 1;
    vb2 ^= 1;
  }

  // ---- cross-half merge (once): __syncthreads drains all DMA before LDS reuse
  lsum += __shfl(lsum, l ^ 32);             // combine lane k-halves (same q)
  __syncthreads();
  float* const Osh  = (float*)smem;                         // 16 KB
  float2* const MLsh = (float2*)((char*)smem + 16384);      // 1 KB

  if (hr == 1){
    #pragma unroll
    for (int r = 0; r < 16; ++r){
      Osh[wr*2048 + l*32 + r]      = o0[r];
      Osh[wr*2048 + l*32 + 16 + r] = o1[r];
    }
    MLsh[wr*64 + l] = float2{m, lsum};
  }
  __syncthreads();

  if (hr == 0){
    const float2 ml1 = MLsh[wr*64 + l];
    const float mm = fmaxf(m, ml1.x);
    const float c0 = exp2f((m - mm) * CEXP);
    const float c1 = exp2f((ml1.x - mm) * CEXP);
    const float lm = lsum*c0 + ml1.y*c1;    // >0 always (half-0 non-empty)
    const float a0q = c0 / lm;
    const float a1q = c1 / lm;
    #pragma unroll
    for (int r = 0; r < 16; ++r){
      const int row = (r & 3) + 8*(r >> 2) + 4*(l >> 5);
      const float f0 = __shfl(a0q, row | (l & 32));
      const float f1 = __shfl(a1q, row | (l & 32));
      const int qg = q0 + row;
      u16* op = aout + (size_t)(b*SEQ + qg) * HIDDEN + h*64 + (l & 31);
      op[0]  = f2bf(o0[r]*f0 + Osh[wr*2048 + l*32 + r]*f1);
      op[32] = f2bf(o1[r]*f0 + Osh[wr*2048 + l*32 + 16 + r]*f1);
    }
  }
}

// ---------------- launch ----------------
extern "C" void kernel_launch(void* const* d_in, const int* in_sizes, int n_in,
                              void* d_out, int out_size, void* d_ws, size_t ws_size,
                              hipStream_t stream){
  const float* enc    = (const float*)d_in[0];
  const float* attn_w = (const float*)d_in[1];
  const float* attn_b = (const float*)d_in[2];
  const float* out_w  = (const float*)d_in[3];
  const float* out_b  = (const float*)d_in[4];

  char* ws = (char*)d_ws;
  u16* enc_bf = (u16*)(ws);
  u16* wa_bf  = (u16*)(ws + (size_t)( 8u << 20));
  u16* wo_bf  = (u16*)(ws + (size_t)(14u << 20));
  u16* qkv    = (u16*)(ws + (size_t)(16u << 20));
  u16* aout   = enc_bf;  // safe alias: attn runs strictly after GEMM1

  k_cvt3<<<dim3((CVT_N0+CVT_N1+CVT_N2 + 255)/256), 256, 0, stream>>>(
      enc, attn_w, out_w, enc_bf, wa_bf, wo_bf);

  k_gemm<QKVC,  true ><<<dim3(MROWS/128, QKVC/128),  256, 0, stream>>>(enc_bf, wa_bf, attn_b, qkv);
  k_attn<<<dim3(32, 32), 256, 0, stream>>>(qkv, aout);
  k_gemm<HIDDEN, false><<<dim3(MROWS/128, HIDDEN/128), 256, 0, stream>>>(aout, wo_bf, out_b, d_out);
}